// Round 4
// baseline (593.490 us; speedup 1.0000x reference)
//
#include <hip/hip_runtime.h>
#include <hip/hip_bf16.h>

#define EPSQ 1e-7f

#define BSZ 128
#define M2 4608           // B*36 conv2 output positions
#define K2 20736          // 81*256
#define KSTEPS 648        // K2/32

// ws offsets in floats (liveness-overlapped).
// c1 hi/lo occupy floats [0, 13107200) until conv2 done; w2t [13107200, 18415616).
// After conv2: PC/S1P/S2P/V1 reuse the dead c1 region; H* reuse dead w2t region.
#define WS_C1H   0              // ushort* (13,107,200 ushorts)
#define WS_C1L   6553600        // floats offset (ushort* view)
#define WS_W2TH  13107200
#define WS_W2TL  15761408
#define WS_CPART 18415616       // k * 1,179,648 floats
#define WS_PC    0              // 1,179,648 fl (written after conv2; c1 dead)
#define WS_S1P   1179648        // 288*20480 = 5,898,240
#define WS_S2P   7077888        // 5,898,240
#define WS_V1    12976128       // 20,480 (ends 12,996,608 < 13,107,200)
#define WS_H0    13107200       // 20,480 (w2t dead)
#define WS_H1    13127680       // 65,536
#define WS_H2    13193216       // 131,072

#define RIC 4                   // i's per routing block
#define RNB 288                 // 1152/RIC

typedef __attribute__((ext_vector_type(8))) short short8;
typedef __attribute__((ext_vector_type(4))) float floatx4;

__device__ inline ushort bf16_rne(float x) {
    union { float f; unsigned u; } v; v.f = x;
    unsigned r = v.u + 0x7FFFu + ((v.u >> 16) & 1u);
    return (ushort)(r >> 16);
}
__device__ inline float bf16_to_f(ushort h) {
    union { unsigned u; float f; } v; v.u = ((unsigned)h) << 16;
    return v.f;
}

// ---------------- conv1: 28x28x1 -> 20x20x256, relu, emit bf16 hi/lo -----------
__global__ __launch_bounds__(256) void conv1_kernel(const float* __restrict__ img,
        const float* __restrict__ w1, const float* __restrict__ b1,
        ushort* __restrict__ c1h, ushort* __restrict__ c1l) {
    int bid = blockIdx.x;            // b*20 + oh
    int b = bid / 20, oh = bid % 20;
    __shared__ float simg[252];
    int t = threadIdx.x;
    if (t < 252) simg[t] = img[b * 784 + oh * 28 + t];
    __syncthreads();
    float acc[20];
#pragma unroll
    for (int ow = 0; ow < 20; ++ow) acc[ow] = 0.f;
    for (int kh = 0; kh < 9; ++kh) {
#pragma unroll
        for (int kw = 0; kw < 9; ++kw) {
            float wv = w1[(kh * 9 + kw) * 256 + t];
            const float* sp = &simg[kh * 28 + kw];
#pragma unroll
            for (int ow = 0; ow < 20; ++ow) acc[ow] += sp[ow] * wv;
        }
    }
    float bias = b1[t];
    size_t opos = ((size_t)(b * 20 + oh) * 20) * 256 + t;
#pragma unroll
    for (int ow = 0; ow < 20; ++ow) {
        float x = fmaxf(acc[ow] + bias, 0.f);
        ushort h = bf16_rne(x);
        c1h[opos + (size_t)ow * 256] = h;
        c1l[opos + (size_t)ow * 256] = bf16_rne(x - bf16_to_f(h));
    }
}

// -------- w2 [20736][256] fp32 -> w2t hi/lo [256][20736] bf16 -------------------
__global__ __launch_bounds__(256) void prep_w2t_kernel(const float* __restrict__ w2,
        ushort* __restrict__ w2th, ushort* __restrict__ w2tl) {
    int kt = blockIdx.x, nt = blockIdx.y;   // 324 x 4
    __shared__ float tile[64][65];
    int t = threadIdx.x;
    int tn = t & 63, t4 = t >> 6;
#pragma unroll
    for (int i = 0; i < 16; ++i) {
        int k = i * 4 + t4;
        tile[k][tn] = w2[(size_t)(kt * 64 + k) * 256 + nt * 64 + tn];
    }
    __syncthreads();
    int tk = t & 63;
#pragma unroll
    for (int i = 0; i < 16; ++i) {
        int n = i * 4 + t4;
        float x = tile[tk][n];
        ushort h = bf16_rne(x);
        ushort lo = bf16_rne(x - bf16_to_f(h));
        size_t o = (size_t)(nt * 64 + n) * 20736 + kt * 64 + tk;
        w2th[o] = h; w2tl[o] = lo;
    }
}

// -------- conv2 MFMA GEMM: split bf16 (hi/lo, 3 terms), fp32 partials -----------
// BM=64, BN=128, BK=32, grid (2, 72, KSPLIT), 4 waves/block.
// LDS rows 32 ushorts (64B) with XOR slot swizzle: slotX = slot ^ ((row>>1)&3)
// -> even bank spread (2-way max) on both ds_write and ds_read_b128.
#define AHO 0
#define ALO 2048
#define BHO 4096
#define BLO 8192
__global__ __launch_bounds__(256) void conv2_mfma_kernel(
        const ushort* __restrict__ c1h, const ushort* __restrict__ c1l,
        const ushort* __restrict__ w2th, const ushort* __restrict__ w2tl,
        float* __restrict__ part, int ktper) {
    int nt = blockIdx.x, mt = blockIdx.y, ks = blockIdx.z;
    int t = threadIdx.x;
    int m0 = mt * 64, n0 = nt * 128;
    __shared__ __attribute__((aligned(16))) ushort lds[12288];   // 24 KB

    int sr = t >> 2, ss = t & 3;
    int m = m0 + sr;
    int b = m / 36, rem = m % 36;
    int posbase = ((b * 20 + (rem / 6) * 2) * 20 + (rem % 6) * 2) * 256;
    int slotX = (ss ^ ((sr >> 1) & 3)) * 8;
    int swA  = sr * 32 + slotX;
    int swB1 = (sr + 64) * 32 + slotX;
    size_t bbase0 = (size_t)(n0 + sr) * 20736 + ss * 8;
    size_t bbase1 = bbase0 + (size_t)64 * 20736;

    int lane = t & 63, wave = t >> 6;
    int l15 = lane & 15, g = lane >> 4;
    int wrb = (wave >> 1) * 32, wcb = (wave & 1) * 64;

    floatx4 acc[2][4];
#pragma unroll
    for (int mi = 0; mi < 2; ++mi)
#pragma unroll
        for (int nj = 0; nj < 4; ++nj) acc[mi][nj] = (floatx4)0.f;

    int kt0 = ks * ktper, kt1 = kt0 + ktper;
    uint4 rah, ral, rb0, rb1, rb2, rb3;
#define LOADG(KT) { \
        int kbase = (KT) * 32; \
        int khkw = kbase >> 8; int kh = khkw / 9, kw = khkw - kh * 9; \
        int aoff = posbase + (kh * 20 + kw) * 256 + (kbase & 255) + ss * 8; \
        rah = *(const uint4*)(c1h + aoff); \
        ral = *(const uint4*)(c1l + aoff); \
        rb0 = *(const uint4*)(w2th + bbase0 + kbase); \
        rb1 = *(const uint4*)(w2th + bbase1 + kbase); \
        rb2 = *(const uint4*)(w2tl + bbase0 + kbase); \
        rb3 = *(const uint4*)(w2tl + bbase1 + kbase); }

    LOADG(kt0);
    for (int kt = kt0; kt < kt1; ++kt) {
        __syncthreads();                    // all waves done reading LDS
        *(uint4*)&lds[AHO + swA]  = rah;
        *(uint4*)&lds[ALO + swA]  = ral;
        *(uint4*)&lds[BHO + swA]  = rb0;
        *(uint4*)&lds[BHO + swB1] = rb1;
        *(uint4*)&lds[BLO + swA]  = rb2;
        *(uint4*)&lds[BLO + swB1] = rb3;
        __syncthreads();
        if (kt + 1 < kt1) LOADG(kt + 1);    // prefetch next tile during compute

        short8 ah[2], al[2], bh[4], bl[4];
#pragma unroll
        for (int mi = 0; mi < 2; ++mi) {
            int r = wrb + mi * 16 + l15;
            int ro = r * 32 + ((g ^ ((r >> 1) & 3)) * 8);
            ah[mi] = *(const short8*)&lds[AHO + ro];
            al[mi] = *(const short8*)&lds[ALO + ro];
        }
#pragma unroll
        for (int nj = 0; nj < 4; ++nj) {
            int c = wcb + nj * 16 + l15;
            int co = c * 32 + ((g ^ ((c >> 1) & 3)) * 8);
            bh[nj] = *(const short8*)&lds[BHO + co];
            bl[nj] = *(const short8*)&lds[BLO + co];
        }
#pragma unroll
        for (int mi = 0; mi < 2; ++mi)
#pragma unroll
            for (int nj = 0; nj < 4; ++nj) {
                acc[mi][nj] = __builtin_amdgcn_mfma_f32_16x16x32_bf16(ah[mi], bh[nj], acc[mi][nj], 0, 0, 0);
                acc[mi][nj] = __builtin_amdgcn_mfma_f32_16x16x32_bf16(ah[mi], bl[nj], acc[mi][nj], 0, 0, 0);
                acc[mi][nj] = __builtin_amdgcn_mfma_f32_16x16x32_bf16(al[mi], bh[nj], acc[mi][nj], 0, 0, 0);
            }
    }
    size_t obase = (size_t)ks * M2 * 256;
#pragma unroll
    for (int mi = 0; mi < 2; ++mi)
#pragma unroll
        for (int nj = 0; nj < 4; ++nj) {
            int col = n0 + wcb + nj * 16 + l15;
            int rowb = m0 + wrb + mi * 16 + (lane >> 4) * 4;
#pragma unroll
            for (int r = 0; r < 4; ++r)
                part[obase + (size_t)(rowb + r) * 256 + col] = acc[mi][nj][r];
        }
}

// -------- reduce k-split partials + bias + relu + squash(8) -> pc ---------------
__global__ __launch_bounds__(256) void squash_pc_kernel(const float* __restrict__ part,
        const float* __restrict__ b2, float* __restrict__ pc, int nsplit) {
    int m = blockIdx.x;
    int n = threadIdx.x;
    size_t idx = (size_t)m * 256 + n;
    const size_t stride = (size_t)M2 * 256;
    float v = 0.f;
    for (int s = 0; s < nsplit; ++s) v += part[idx + s * stride];
    v = fmaxf(v + b2[n], 0.f);
    float sq = v * v;
    sq += __shfl_xor(sq, 1, 8);
    sq += __shfl_xor(sq, 2, 8);
    sq += __shfl_xor(sq, 4, 8);
    float scale = sq / ((1.f + sq) * sqrtf(sq + EPSQ));
    pc[idx] = v * scale;
}

// -------- s1 partials: s1[b,jd] = sum_{i,k} W[i,jd,k] pc[b,i,k] (i-chunked) -----
__global__ __launch_bounds__(192) void s1gemm_kernel(const float* __restrict__ Wm,
        const float* __restrict__ pc, float* __restrict__ s1p) {
    int kc = blockIdx.x; int i0 = kc * RIC;
    int t = threadIdx.x;
    __shared__ float pcl[128 * RIC * 8];       // [b][ii*8+kk]
    for (int e = t; e < 128 * RIC * 8; e += 192) {
        int b = e >> 5, off = e & 31;
        pcl[e] = pc[(size_t)b * 9216 + i0 * 8 + off];
    }
    __syncthreads();
    if (t >= 160) return;
    float4 w[RIC][2];
#pragma unroll
    for (int ii = 0; ii < RIC; ++ii) {
        const float4* wp = (const float4*)&Wm[(size_t)(i0 + ii) * 1280 + t * 8];
        w[ii][0] = wp[0]; w[ii][1] = wp[1];
    }
    for (int b = 0; b < 128; ++b) {
        float s = 0.f;
#pragma unroll
        for (int ii = 0; ii < RIC; ++ii) {
            const float* p = &pcl[b * 32 + ii * 8];
            s += w[ii][0].x * p[0] + w[ii][0].y * p[1] + w[ii][0].z * p[2] + w[ii][0].w * p[3]
               + w[ii][1].x * p[4] + w[ii][1].y * p[5] + w[ii][1].z * p[6] + w[ii][1].w * p[7];
        }
        s1p[(size_t)kc * 20480 + b * 160 + t] = s;
    }
}

// -------- v1 = squash_d(0.1 * sum of partials) ----------------------------------
__global__ __launch_bounds__(192) void v1_kernel(const float* __restrict__ s1p,
        float* __restrict__ v1) {
    int b = blockIdx.x, t = threadIdx.x;
    if (t >= 160) return;
    float s = 0.f;
    for (int kc = 0; kc < RNB; ++kc) s += s1p[(size_t)kc * 20480 + b * 160 + t];
    s *= 0.1f;
    float sq = s * s;
    sq += __shfl_xor(sq, 1, 16);
    sq += __shfl_xor(sq, 2, 16);
    sq += __shfl_xor(sq, 4, 16);
    sq += __shfl_xor(sq, 8, 16);
    v1[b * 160 + t] = s * sq / ((1.f + sq) * sqrtf(sq + EPSQ));
}

// -------- c2 (agreement+softmax) and s2 partials, u recomputed from W,pc --------
__global__ __launch_bounds__(192) void c2s2_kernel(const float* __restrict__ Wm,
        const float* __restrict__ pc, const float* __restrict__ v1,
        float* __restrict__ s2p) {
    int kc = blockIdx.x; int i0 = kc * RIC;
    int t = threadIdx.x;
    __shared__ float pcl[128 * RIC * 8];       // 16 KB
    __shared__ float uvl[RIC][128][10];        // 20 KB
    for (int e = t; e < 128 * RIC * 8; e += 192) {
        int b = e >> 5, off = e & 31;
        pcl[e] = pc[(size_t)b * 9216 + i0 * 8 + off];
    }
    __syncthreads();
    float4 w[RIC][2];
    int j = t >> 4;
    if (t < 160) {
#pragma unroll
        for (int ii = 0; ii < RIC; ++ii) {
            const float4* wp = (const float4*)&Wm[(size_t)(i0 + ii) * 1280 + t * 8];
            w[ii][0] = wp[0]; w[ii][1] = wp[1];
        }
        for (int b = 0; b < 128; ++b) {
            float vv = v1[b * 160 + t];
#pragma unroll
            for (int ii = 0; ii < RIC; ++ii) {
                const float* p = &pcl[b * 32 + ii * 8];
                float u = w[ii][0].x * p[0] + w[ii][0].y * p[1] + w[ii][0].z * p[2] + w[ii][0].w * p[3]
                        + w[ii][1].x * p[4] + w[ii][1].y * p[5] + w[ii][1].z * p[6] + w[ii][1].w * p[7];
                float pr = u * vv;
                pr += __shfl_xor(pr, 1, 16);
                pr += __shfl_xor(pr, 2, 16);
                pr += __shfl_xor(pr, 4, 16);
                pr += __shfl_xor(pr, 8, 16);
                if ((t & 15) == 0) uvl[ii][b][j] = pr;
            }
        }
    }
    __syncthreads();
    // softmax over j for each (ii, b)
    for (int e = t; e < RIC * 128; e += 192) {
        int ii = e >> 7, b = e & 127;
        float* uv = uvl[ii][b];
        float mx = uv[0];
#pragma unroll
        for (int jj = 1; jj < 10; ++jj) mx = fmaxf(mx, uv[jj]);
        float sum = 0.f;
        float ex[10];
#pragma unroll
        for (int jj = 0; jj < 10; ++jj) { ex[jj] = expf(uv[jj] - mx); sum += ex[jj]; }
        float inv = 1.f / sum;
#pragma unroll
        for (int jj = 0; jj < 10; ++jj) uv[jj] = ex[jj] * inv;
    }
    __syncthreads();
    if (t >= 160) return;
    for (int b = 0; b < 128; ++b) {
        float acc = 0.f;
#pragma unroll
        for (int ii = 0; ii < RIC; ++ii) {
            const float* p = &pcl[b * 32 + ii * 8];
            float u = w[ii][0].x * p[0] + w[ii][0].y * p[1] + w[ii][0].z * p[2] + w[ii][0].w * p[3]
                    + w[ii][1].x * p[4] + w[ii][1].y * p[5] + w[ii][1].z * p[6] + w[ii][1].w * p[7];
            acc += uvl[ii][b][j] * u;
        }
        s2p[(size_t)kc * 20480 + b * 160 + t] = acc;
    }
}

// -------- v2, norms, argmax, masked decoder input -------------------------------
__global__ __launch_bounds__(192) void v2norm_kernel(const float* __restrict__ s2p,
        const int* __restrict__ target, float* __restrict__ out,
        float* __restrict__ h0) {
    int b = blockIdx.x, t = threadIdx.x;
    int j = t >> 4;
    __shared__ float nrm[10];
    float v = 0.f;
    if (t < 160) {
        float s = 0.f;
        for (int kc = 0; kc < RNB; ++kc) s += s2p[(size_t)kc * 20480 + b * 160 + t];
        float sq = s * s;
        sq += __shfl_xor(sq, 1, 16);
        sq += __shfl_xor(sq, 2, 16);
        sq += __shfl_xor(sq, 4, 16);
        sq += __shfl_xor(sq, 8, 16);
        v = s * sq / ((1.f + sq) * sqrtf(sq + EPSQ));
        float vsq = v * v;
        vsq += __shfl_xor(vsq, 1, 16);
        vsq += __shfl_xor(vsq, 2, 16);
        vsq += __shfl_xor(vsq, 4, 16);
        vsq += __shfl_xor(vsq, 8, 16);
        float norm = sqrtf(vsq + EPSQ);
        if ((t & 15) == 0) { nrm[j] = norm; out[b * 10 + j] = norm; }
    }
    __syncthreads();
    if (t == 0) {
        float best = nrm[0]; int am = 0;
#pragma unroll
        for (int jj = 1; jj < 10; ++jj) if (nrm[jj] > best) { best = nrm[jj]; am = jj; }
        out[1280 + b] = (float)am;
    }
    if (t < 160) h0[b * 160 + t] = (j == target[b]) ? v : 0.f;
}

// -------- dense layers: relu (ACT=0) or sigmoid (ACT=1) -------------------------
template <int KDIM, int ACT>
__global__ __launch_bounds__(256) void fc_kernel(const float* __restrict__ in,
        const float* __restrict__ w, const float* __restrict__ bias,
        float* __restrict__ out, int N) {
    int b = blockIdx.y;
    int n = blockIdx.x * 256 + threadIdx.x;
    __shared__ float sk[KDIM];
    for (int r = threadIdx.x; r < KDIM; r += 256) sk[r] = in[(size_t)b * KDIM + r];
    __syncthreads();
    if (n >= N) return;
    float acc = bias[n];
    for (int k = 0; k < KDIM; ++k) acc += sk[k] * w[(size_t)k * N + n];
    if (ACT == 0) acc = fmaxf(acc, 0.f);
    else acc = 1.f / (1.f + expf(-acc));
    out[(size_t)b * N + n] = acc;
}

extern "C" void kernel_launch(void* const* d_in, const int* in_sizes, int n_in,
                              void* d_out, int out_size, void* d_ws, size_t ws_size,
                              hipStream_t stream) {
    const float* image = (const float*)d_in[0];
    const int*   target = (const int*)d_in[1];
    const float* w1  = (const float*)d_in[2];
    const float* b1  = (const float*)d_in[3];
    const float* w2  = (const float*)d_in[4];
    const float* b2  = (const float*)d_in[5];
    const float* Wm  = (const float*)d_in[6];
    const float* d1w = (const float*)d_in[7];
    const float* d1b = (const float*)d_in[8];
    const float* d2w = (const float*)d_in[9];
    const float* d2b = (const float*)d_in[10];
    const float* dow = (const float*)d_in[11];
    const float* dob = (const float*)d_in[12];
    float* out = (float*)d_out;
    float* ws  = (float*)d_ws;

    ushort* c1h  = (ushort*)(ws + WS_C1H);
    ushort* c1l  = (ushort*)(ws + WS_C1L);
    ushort* w2th = (ushort*)(ws + WS_W2TH);
    ushort* w2tl = (ushort*)(ws + WS_W2TL);

    // adaptive k-split by available workspace: need (18,415,616 + k*1,179,648)*4 B
    int ksplit = 4;
    if (ws_size >= (size_t)(18415616 + 8 * 1179648) * 4) ksplit = 8;
    else if (ws_size >= (size_t)(18415616 + 6 * 1179648) * 4) ksplit = 6;
    int ktper = KSTEPS / ksplit;

    conv1_kernel<<<2560, 256, 0, stream>>>(image, w1, b1, c1h, c1l);
    prep_w2t_kernel<<<dim3(324, 4), 256, 0, stream>>>(w2, w2th, w2tl);
    conv2_mfma_kernel<<<dim3(2, 72, ksplit), 256, 0, stream>>>(c1h, c1l, w2th, w2tl,
                                                               ws + WS_CPART, ktper);
    squash_pc_kernel<<<4608, 256, 0, stream>>>(ws + WS_CPART, b2, ws + WS_PC, ksplit);
    s1gemm_kernel<<<RNB, 192, 0, stream>>>(Wm, ws + WS_PC, ws + WS_S1P);
    v1_kernel<<<128, 192, 0, stream>>>(ws + WS_S1P, ws + WS_V1);
    c2s2_kernel<<<RNB, 192, 0, stream>>>(Wm, ws + WS_PC, ws + WS_V1, ws + WS_S2P);
    v2norm_kernel<<<128, 192, 0, stream>>>(ws + WS_S2P, target, out, ws + WS_H0);
    fc_kernel<160, 0><<<dim3(2, 128), 256, 0, stream>>>(ws + WS_H0, d1w, d1b, ws + WS_H1, 512);
    fc_kernel<512, 0><<<dim3(4, 128), 256, 0, stream>>>(ws + WS_H1, d2w, d2b, ws + WS_H2, 1024);
    fc_kernel<1024, 1><<<dim3(4, 128), 256, 0, stream>>>(ws + WS_H2, dow, dob, out + 1408, 784);
}

// Round 5
// 534.072 us; speedup vs baseline: 1.1113x; 1.1113x over previous
//
#include <hip/hip_runtime.h>
#include <hip/hip_bf16.h>

#define EPSQ 1e-7f

#define BSZ 128
#define M2 4608           // B*36 conv2 output positions
#define K2 20736          // 81*256
#define KSTEPS 648        // K2/32

// ws offsets in floats (liveness-overlapped).
// Phase 1 (conv): c1 hi/lo [0, 13,107,200), w2t hi/lo [13,107,200, 18,415,616),
//                 CPART [18,415,616, +ksplit*1,179,648)   (<= 130.3 MB at ksplit=12)
// Phase 2 (routing): PC/S1P/S2P/V1/V2/NRM reuse dead-c1; H1/H2 reuse dead-w2t.
#define WS_C1H   0
#define WS_C1L   6553600
#define WS_W2TH  13107200
#define WS_W2TL  15761408
#define WS_CPART 18415616
#define WS_PC    0              // 1,179,648 fl
#define WS_S1P   1179648        // 144*20480 = 2,949,120 fl
#define WS_S2P   4128768        // 2,949,120 fl
#define WS_V1    7077888        // 20,480
#define WS_V2    7098368        // 20,480
#define WS_NRM   7118848        // 1,280  (ends 7,120,128 < 13,107,200 ok)
#define WS_H1    13107200       // 65,536
#define WS_H2    13172736       // 131,072 (ends 13,303,808 < 18,415,616 ok)

typedef __attribute__((ext_vector_type(8))) short short8;
typedef __attribute__((ext_vector_type(4))) float floatx4;

#define DOT8(W0, W1, P) ((W0).x*(P)[0] + (W0).y*(P)[1] + (W0).z*(P)[2] + (W0).w*(P)[3] + \
                         (W1).x*(P)[4] + (W1).y*(P)[5] + (W1).z*(P)[6] + (W1).w*(P)[7])

__device__ inline ushort bf16_rne(float x) {
    union { float f; unsigned u; } v; v.f = x;
    unsigned r = v.u + 0x7FFFu + ((v.u >> 16) & 1u);
    return (ushort)(r >> 16);
}
__device__ inline float bf16_to_f(ushort h) {
    union { unsigned u; float f; } v; v.u = ((unsigned)h) << 16;
    return v.f;
}

// ---------------- conv1: 28x28x1 -> 20x20x256, relu, emit bf16 hi/lo -----------
// Register-row version: 252 ds_reads/thread (was 1620) — conv1 was LDS-issue-bound.
__global__ __launch_bounds__(256) void conv1_kernel(const float* __restrict__ img,
        const float* __restrict__ w1, const float* __restrict__ b1,
        ushort* __restrict__ c1h, ushort* __restrict__ c1l) {
    int bid = blockIdx.x;            // b*20 + oh
    int b = bid / 20, oh = bid % 20;
    __shared__ float simg[252];
    int t = threadIdx.x;
    if (t < 252) simg[t] = img[b * 784 + oh * 28 + t];
    __syncthreads();
    float acc[20];
#pragma unroll
    for (int ow = 0; ow < 20; ++ow) acc[ow] = 0.f;
    for (int kh = 0; kh < 9; ++kh) {
        float row[28];
#pragma unroll
        for (int c = 0; c < 28; ++c) row[c] = simg[kh * 28 + c];
#pragma unroll
        for (int kw = 0; kw < 9; ++kw) {
            float wv = w1[(kh * 9 + kw) * 256 + t];
#pragma unroll
            for (int ow = 0; ow < 20; ++ow) acc[ow] += row[kw + ow] * wv;
        }
    }
    float bias = b1[t];
    size_t opos = ((size_t)(b * 20 + oh) * 20) * 256 + t;
#pragma unroll
    for (int ow = 0; ow < 20; ++ow) {
        float x = fmaxf(acc[ow] + bias, 0.f);
        ushort h = bf16_rne(x);
        c1h[opos + (size_t)ow * 256] = h;
        c1l[opos + (size_t)ow * 256] = bf16_rne(x - bf16_to_f(h));
    }
}

// -------- w2 [20736][256] fp32 -> w2t hi/lo [256][20736] bf16 -------------------
__global__ __launch_bounds__(256) void prep_w2t_kernel(const float* __restrict__ w2,
        ushort* __restrict__ w2th, ushort* __restrict__ w2tl) {
    int kt = blockIdx.x, nt = blockIdx.y;   // 324 x 4
    __shared__ float tile[64][65];
    int t = threadIdx.x;
    int tn = t & 63, t4 = t >> 6;
#pragma unroll
    for (int i = 0; i < 16; ++i) {
        int k = i * 4 + t4;
        tile[k][tn] = w2[(size_t)(kt * 64 + k) * 256 + nt * 64 + tn];
    }
    __syncthreads();
    int tk = t & 63;
#pragma unroll
    for (int i = 0; i < 16; ++i) {
        int n = i * 4 + t4;
        float x = tile[tk][n];
        ushort h = bf16_rne(x);
        ushort lo = bf16_rne(x - bf16_to_f(h));
        size_t o = (size_t)(nt * 64 + n) * 20736 + kt * 64 + tk;
        w2th[o] = h; w2tl[o] = lo;
    }
}

// -------- conv2 MFMA GEMM: split bf16 (hi/lo, 3 terms), fp32 partials -----------
// BM=64, BN=128, BK=32, grid (2, 72, KSPLIT), 4 waves/block. XOR slot swizzle
// (verified: bank conflicts 3.6e7 -> 0). Register prefetch of next k-tile.
#define AHO 0
#define ALO 2048
#define BHO 4096
#define BLO 8192
__global__ __launch_bounds__(256) void conv2_mfma_kernel(
        const ushort* __restrict__ c1h, const ushort* __restrict__ c1l,
        const ushort* __restrict__ w2th, const ushort* __restrict__ w2tl,
        float* __restrict__ part, int ktper) {
    int nt = blockIdx.x, mt = blockIdx.y, ks = blockIdx.z;
    int t = threadIdx.x;
    int m0 = mt * 64, n0 = nt * 128;
    __shared__ __attribute__((aligned(16))) ushort lds[12288];   // 24 KB

    int sr = t >> 2, ss = t & 3;
    int m = m0 + sr;
    int b = m / 36, rem = m % 36;
    int posbase = ((b * 20 + (rem / 6) * 2) * 20 + (rem % 6) * 2) * 256;
    int slotX = (ss ^ ((sr >> 1) & 3)) * 8;
    int swA  = sr * 32 + slotX;
    int swB1 = (sr + 64) * 32 + slotX;
    size_t bbase0 = (size_t)(n0 + sr) * 20736 + ss * 8;
    size_t bbase1 = bbase0 + (size_t)64 * 20736;

    int lane = t & 63, wave = t >> 6;
    int l15 = lane & 15, g = lane >> 4;
    int wrb = (wave >> 1) * 32, wcb = (wave & 1) * 64;

    floatx4 acc[2][4];
#pragma unroll
    for (int mi = 0; mi < 2; ++mi)
#pragma unroll
        for (int nj = 0; nj < 4; ++nj) acc[mi][nj] = (floatx4)0.f;

    int kt0 = ks * ktper, kt1 = kt0 + ktper;
    uint4 rah, ral, rb0, rb1, rb2, rb3;
#define LOADG(KT) { \
        int kbase = (KT) * 32; \
        int khkw = kbase >> 8; int kh = khkw / 9, kw = khkw - kh * 9; \
        int aoff = posbase + (kh * 20 + kw) * 256 + (kbase & 255) + ss * 8; \
        rah = *(const uint4*)(c1h + aoff); \
        ral = *(const uint4*)(c1l + aoff); \
        rb0 = *(const uint4*)(w2th + bbase0 + kbase); \
        rb1 = *(const uint4*)(w2th + bbase1 + kbase); \
        rb2 = *(const uint4*)(w2tl + bbase0 + kbase); \
        rb3 = *(const uint4*)(w2tl + bbase1 + kbase); }

    LOADG(kt0);
    for (int kt = kt0; kt < kt1; ++kt) {
        __syncthreads();                    // all waves done reading LDS
        *(uint4*)&lds[AHO + swA]  = rah;
        *(uint4*)&lds[ALO + swA]  = ral;
        *(uint4*)&lds[BHO + swA]  = rb0;
        *(uint4*)&lds[BHO + swB1] = rb1;
        *(uint4*)&lds[BLO + swA]  = rb2;
        *(uint4*)&lds[BLO + swB1] = rb3;
        __syncthreads();
        if (kt + 1 < kt1) LOADG(kt + 1);    // prefetch next tile during compute

        short8 ah[2], al[2], bh[4], bl[4];
#pragma unroll
        for (int mi = 0; mi < 2; ++mi) {
            int r = wrb + mi * 16 + l15;
            int ro = r * 32 + ((g ^ ((r >> 1) & 3)) * 8);
            ah[mi] = *(const short8*)&lds[AHO + ro];
            al[mi] = *(const short8*)&lds[ALO + ro];
        }
#pragma unroll
        for (int nj = 0; nj < 4; ++nj) {
            int c = wcb + nj * 16 + l15;
            int co = c * 32 + ((g ^ ((c >> 1) & 3)) * 8);
            bh[nj] = *(const short8*)&lds[BHO + co];
            bl[nj] = *(const short8*)&lds[BLO + co];
        }
#pragma unroll
        for (int mi = 0; mi < 2; ++mi)
#pragma unroll
            for (int nj = 0; nj < 4; ++nj) {
                acc[mi][nj] = __builtin_amdgcn_mfma_f32_16x16x32_bf16(ah[mi], bh[nj], acc[mi][nj], 0, 0, 0);
                acc[mi][nj] = __builtin_amdgcn_mfma_f32_16x16x32_bf16(ah[mi], bl[nj], acc[mi][nj], 0, 0, 0);
                acc[mi][nj] = __builtin_amdgcn_mfma_f32_16x16x32_bf16(al[mi], bh[nj], acc[mi][nj], 0, 0, 0);
            }
    }
    size_t obase = (size_t)ks * M2 * 256;
#pragma unroll
    for (int mi = 0; mi < 2; ++mi)
#pragma unroll
        for (int nj = 0; nj < 4; ++nj) {
            int col = n0 + wcb + nj * 16 + l15;
            int rowb = m0 + wrb + mi * 16 + (lane >> 4) * 4;
#pragma unroll
            for (int r = 0; r < 4; ++r)
                part[obase + (size_t)(rowb + r) * 256 + col] = acc[mi][nj][r];
        }
}

// -------- reduce k-split partials + bias + relu + squash(8) -> pc ---------------
__global__ __launch_bounds__(256) void squash_pc_kernel(const float* __restrict__ part,
        const float* __restrict__ b2, float* __restrict__ pc, int nsplit) {
    int m = blockIdx.x;
    int n = threadIdx.x;
    size_t idx = (size_t)m * 256 + n;
    const size_t stride = (size_t)M2 * 256;
    float v = 0.f;
    for (int s = 0; s < nsplit; ++s) v += part[idx + s * stride];
    v = fmaxf(v + b2[n], 0.f);
    float sq = v * v;
    sq += __shfl_xor(sq, 1, 8);
    sq += __shfl_xor(sq, 2, 8);
    sq += __shfl_xor(sq, 4, 8);
    float scale = sq / ((1.f + sq) * sqrtf(sq + EPSQ));
    pc[idx] = v * scale;
}

// -------- s1 partials: grid (144 i-chunks x 8 b-groups), W in regs --------------
__global__ __launch_bounds__(192) void s1part_kernel(const float* __restrict__ Wm,
        const float* __restrict__ pc, float* __restrict__ s1p) {
    int ic = blockIdx.x, bg = blockIdx.y;
    int i0 = ic * 8, b0 = bg * 16;
    int t = threadIdx.x;
    __shared__ float pcl[16][68];
    for (int e = t; e < 1024; e += 192) {
        int bl = e >> 6, off = e & 63;
        pcl[bl][off] = pc[(size_t)(b0 + bl) * 9216 + i0 * 8 + off];
    }
    __syncthreads();
    if (t >= 160) return;
    float4 w[8][2];
#pragma unroll
    for (int ii = 0; ii < 8; ++ii) {
        const float4* wp = (const float4*)&Wm[(size_t)(i0 + ii) * 1280 + t * 8];
        w[ii][0] = wp[0]; w[ii][1] = wp[1];
    }
    for (int bl = 0; bl < 16; ++bl) {
        float s = 0.f;
#pragma unroll
        for (int ii = 0; ii < 8; ++ii) {
            const float* p = &pcl[bl][ii * 8];
            s += DOT8(w[ii][0], w[ii][1], p);
        }
        s1p[(size_t)ic * 20480 + (b0 + bl) * 160 + t] = s;
    }
}

// -------- v1 = squash_d(0.1 * sum of 144 partials), grid (b*10+j) ---------------
__global__ __launch_bounds__(64) void v1red_kernel(const float* __restrict__ s1p,
        float* __restrict__ v1) {
    int bj = blockIdx.x;
    int b = bj / 10, j = bj % 10;
    int t = threadIdx.x;
    int d = t & 15, kq = t >> 4;
    size_t base = (size_t)b * 160 + j * 16 + d;
    float s = 0.f;
    for (int kc = kq; kc < 144; kc += 4) s += s1p[(size_t)kc * 20480 + base];
    s += __shfl_xor(s, 16, 64);
    s += __shfl_xor(s, 32, 64);
    s *= 0.1f;
    float sq = s * s;
    sq += __shfl_xor(sq, 1, 16);
    sq += __shfl_xor(sq, 2, 16);
    sq += __shfl_xor(sq, 4, 16);
    sq += __shfl_xor(sq, 8, 16);
    float v = s * sq / ((1.f + sq) * sqrtf(sq + EPSQ));
    if (t < 16) v1[b * 160 + j * 16 + d] = v;
}

// -------- c2 (agreement+softmax) + s2 partials, u recomputed; grid (144 x 8) ----
__global__ __launch_bounds__(192) void c2s2_kernel(const float* __restrict__ Wm,
        const float* __restrict__ pc, const float* __restrict__ v1,
        float* __restrict__ s2p) {
    int ic = blockIdx.x, bg = blockIdx.y;
    int i0 = ic * 8, b0 = bg * 16;
    int t = threadIdx.x;
    __shared__ float pcl[16][68];
    __shared__ float uvl[8][16][10];
    for (int e = t; e < 1024; e += 192) {
        int bl = e >> 6, off = e & 63;
        pcl[bl][off] = pc[(size_t)(b0 + bl) * 9216 + i0 * 8 + off];
    }
    __syncthreads();
    int j = t >> 4;
    float4 w[8][2];
    if (t < 160) {
#pragma unroll
        for (int ii = 0; ii < 8; ++ii) {
            const float4* wp = (const float4*)&Wm[(size_t)(i0 + ii) * 1280 + t * 8];
            w[ii][0] = wp[0]; w[ii][1] = wp[1];
        }
        for (int bl = 0; bl < 16; ++bl) {
            float vv = v1[(b0 + bl) * 160 + t];
#pragma unroll
            for (int ii = 0; ii < 8; ++ii) {
                const float* p = &pcl[bl][ii * 8];
                float u = DOT8(w[ii][0], w[ii][1], p);
                float pr = u * vv;
                pr += __shfl_xor(pr, 1, 16);
                pr += __shfl_xor(pr, 2, 16);
                pr += __shfl_xor(pr, 4, 16);
                pr += __shfl_xor(pr, 8, 16);
                if ((t & 15) == 0) uvl[ii][bl][j] = pr;
            }
        }
    }
    __syncthreads();
    if (t < 128) {
        int ii = t >> 4, bl = t & 15;
        float* uv = uvl[ii][bl];
        float mx = uv[0];
#pragma unroll
        for (int jj = 1; jj < 10; ++jj) mx = fmaxf(mx, uv[jj]);
        float sum = 0.f;
        float ex[10];
#pragma unroll
        for (int jj = 0; jj < 10; ++jj) { ex[jj] = expf(uv[jj] - mx); sum += ex[jj]; }
        float inv = 1.f / sum;
#pragma unroll
        for (int jj = 0; jj < 10; ++jj) uv[jj] = ex[jj] * inv;
    }
    __syncthreads();
    if (t >= 160) return;
    for (int bl = 0; bl < 16; ++bl) {
        float acc = 0.f;
#pragma unroll
        for (int ii = 0; ii < 8; ++ii) {
            const float* p = &pcl[bl][ii * 8];
            float u = DOT8(w[ii][0], w[ii][1], p);
            acc += uvl[ii][bl][j] * u;
        }
        s2p[(size_t)ic * 20480 + (b0 + bl) * 160 + t] = acc;
    }
}

// -------- v2 = squash_d(sum partials), norms -> out, grid (b*10+j) --------------
__global__ __launch_bounds__(64) void v2red_kernel(const float* __restrict__ s2p,
        float* __restrict__ v2, float* __restrict__ nrm, float* __restrict__ out) {
    int bj = blockIdx.x;
    int b = bj / 10, j = bj % 10;
    int t = threadIdx.x;
    int d = t & 15, kq = t >> 4;
    size_t base = (size_t)b * 160 + j * 16 + d;
    float s = 0.f;
    for (int kc = kq; kc < 144; kc += 4) s += s2p[(size_t)kc * 20480 + base];
    s += __shfl_xor(s, 16, 64);
    s += __shfl_xor(s, 32, 64);
    float sq = s * s;
    sq += __shfl_xor(sq, 1, 16);
    sq += __shfl_xor(sq, 2, 16);
    sq += __shfl_xor(sq, 4, 16);
    sq += __shfl_xor(sq, 8, 16);
    float v = s * sq / ((1.f + sq) * sqrtf(sq + EPSQ));
    float vsq = v * v;
    vsq += __shfl_xor(vsq, 1, 16);
    vsq += __shfl_xor(vsq, 2, 16);
    vsq += __shfl_xor(vsq, 4, 16);
    vsq += __shfl_xor(vsq, 8, 16);
    float norm = sqrtf(vsq + EPSQ);
    if (t < 16) v2[b * 160 + j * 16 + d] = v;
    if (t == 0) { nrm[b * 10 + j] = norm; out[b * 10 + j] = norm; }
}

// -------- fc1 with fused argmax (y_pred) + target mask --------------------------
__global__ __launch_bounds__(256) void fc1_kernel(const float* __restrict__ v2,
        const float* __restrict__ nrm, const int* __restrict__ target,
        const float* __restrict__ w, const float* __restrict__ bias,
        float* __restrict__ ypred, float* __restrict__ h1) {
    int nc = blockIdx.x, b = blockIdx.y;
    int t = threadIdx.x;
    __shared__ float sk[160];
    __shared__ float nl[10];
    if (t < 160) {
        float v = v2[b * 160 + t];
        sk[t] = ((t >> 4) == target[b]) ? v : 0.f;
    }
    if (t < 10) nl[t] = nrm[b * 10 + t];
    __syncthreads();
    if (nc == 0 && t == 0) {
        float best = nl[0]; int am = 0;
#pragma unroll
        for (int jj = 1; jj < 10; ++jj) if (nl[jj] > best) { best = nl[jj]; am = jj; }
        ypred[b] = (float)am;
    }
    int n = nc * 256 + t;
    float acc = bias[n];
    for (int k = 0; k < 160; ++k) acc += sk[k] * w[k * 512 + n];
    h1[(size_t)b * 512 + n] = fmaxf(acc, 0.f);
}

// -------- dense layers: relu (ACT=0) or sigmoid (ACT=1) -------------------------
template <int KDIM, int ACT>
__global__ __launch_bounds__(256) void fc_kernel(const float* __restrict__ in,
        const float* __restrict__ w, const float* __restrict__ bias,
        float* __restrict__ out, int N) {
    int b = blockIdx.y;
    int n = blockIdx.x * 256 + threadIdx.x;
    __shared__ float sk[KDIM];
    for (int r = threadIdx.x; r < KDIM; r += 256) sk[r] = in[(size_t)b * KDIM + r];
    __syncthreads();
    if (n >= N) return;
    float acc = bias[n];
    for (int k = 0; k < KDIM; ++k) acc += sk[k] * w[(size_t)k * N + n];
    if (ACT == 0) acc = fmaxf(acc, 0.f);
    else acc = 1.f / (1.f + expf(-acc));
    out[(size_t)b * N + n] = acc;
}

extern "C" void kernel_launch(void* const* d_in, const int* in_sizes, int n_in,
                              void* d_out, int out_size, void* d_ws, size_t ws_size,
                              hipStream_t stream) {
    const float* image = (const float*)d_in[0];
    const int*   target = (const int*)d_in[1];
    const float* w1  = (const float*)d_in[2];
    const float* b1  = (const float*)d_in[3];
    const float* w2  = (const float*)d_in[4];
    const float* b2  = (const float*)d_in[5];
    const float* Wm  = (const float*)d_in[6];
    const float* d1w = (const float*)d_in[7];
    const float* d1b = (const float*)d_in[8];
    const float* d2w = (const float*)d_in[9];
    const float* d2b = (const float*)d_in[10];
    const float* dow = (const float*)d_in[11];
    const float* dob = (const float*)d_in[12];
    float* out = (float*)d_out;
    float* ws  = (float*)d_ws;

    ushort* c1h  = (ushort*)(ws + WS_C1H);
    ushort* c1l  = (ushort*)(ws + WS_C1L);
    ushort* w2th = (ushort*)(ws + WS_W2TH);
    ushort* w2tl = (ushort*)(ws + WS_W2TL);

    // adaptive k-split: need (18,415,616 + k*1,179,648)*4 bytes of ws
    int ksplit = 4;
    if (ws_size >= (size_t)(18415616 + 12 * 1179648) * 4) ksplit = 12;
    else if (ws_size >= (size_t)(18415616 + 8 * 1179648) * 4) ksplit = 8;
    else if (ws_size >= (size_t)(18415616 + 6 * 1179648) * 4) ksplit = 6;
    int ktper = KSTEPS / ksplit;

    conv1_kernel<<<2560, 256, 0, stream>>>(image, w1, b1, c1h, c1l);
    prep_w2t_kernel<<<dim3(324, 4), 256, 0, stream>>>(w2, w2th, w2tl);
    conv2_mfma_kernel<<<dim3(2, 72, ksplit), 256, 0, stream>>>(c1h, c1l, w2th, w2tl,
                                                               ws + WS_CPART, ktper);
    squash_pc_kernel<<<4608, 256, 0, stream>>>(ws + WS_CPART, b2, ws + WS_PC, ksplit);
    s1part_kernel<<<dim3(144, 8), 192, 0, stream>>>(Wm, ws + WS_PC, ws + WS_S1P);
    v1red_kernel<<<1280, 64, 0, stream>>>(ws + WS_S1P, ws + WS_V1);
    c2s2_kernel<<<dim3(144, 8), 192, 0, stream>>>(Wm, ws + WS_PC, ws + WS_V1, ws + WS_S2P);
    v2red_kernel<<<1280, 64, 0, stream>>>(ws + WS_S2P, ws + WS_V2, ws + WS_NRM, out);
    fc1_kernel<<<dim3(2, 128), 256, 0, stream>>>(ws + WS_V2, ws + WS_NRM, target,
                                                 d1w, d1b, out + 1280, ws + WS_H1);
    fc_kernel<512, 0><<<dim3(4, 128), 256, 0, stream>>>(ws + WS_H1, d2w, d2b, ws + WS_H2, 1024);
    fc_kernel<1024, 1><<<dim3(4, 128), 256, 0, stream>>>(ws + WS_H2, dow, dob, out + 1408, 784);
}

// Round 6
// 516.657 us; speedup vs baseline: 1.1487x; 1.0337x over previous
//
#include <hip/hip_runtime.h>
#include <hip/hip_bf16.h>

#define EPSQ 1e-7f

#define BSZ 128
#define M2 4608           // B*36 conv2 output positions
#define K2 20736          // 81*256
#define KSTEPS 648        // K2/32

// ws offsets in floats (liveness-overlapped).
// Phase 1 (conv): c1 hi/lo [0, 13,107,200), w2t hi/lo [13,107,200, 18,415,616),
//                 CPART [18,415,616, +ksplit*1,179,648)
// Phase 2 (routing): PC/S1P/S2P/V1/V2/NRM reuse dead-c1; H1/H2 reuse dead-w2t.
#define WS_C1H   0
#define WS_C1L   6553600
#define WS_W2TH  13107200
#define WS_W2TL  15761408
#define WS_CPART 18415616
#define WS_PC    0              // 1,179,648 fl
#define WS_S1P   1179648        // 144*20480 = 2,949,120 fl
#define WS_S2P   4128768        // 2,949,120 fl
#define WS_V1    7077888        // 20,480
#define WS_V2    7098368        // 20,480
#define WS_NRM   7118848        // 1,280
#define WS_H1    13107200       // 65,536
#define WS_H2    13172736       // 131,072

typedef __attribute__((ext_vector_type(8))) short short8;
typedef __attribute__((ext_vector_type(4))) float floatx4;

#define DOT8(W0, W1, P) ((W0).x*(P)[0] + (W0).y*(P)[1] + (W0).z*(P)[2] + (W0).w*(P)[3] + \
                         (W1).x*(P)[4] + (W1).y*(P)[5] + (W1).z*(P)[6] + (W1).w*(P)[7])

__device__ inline ushort bf16_rne(float x) {
    union { float f; unsigned u; } v; v.f = x;
    unsigned r = v.u + 0x7FFFu + ((v.u >> 16) & 1u);
    return (ushort)(r >> 16);
}
__device__ inline float bf16_to_f(ushort h) {
    union { unsigned u; float f; } v; v.u = ((unsigned)h) << 16;
    return v.f;
}

// ---------------- conv1: 28x28x1 -> 20x20x256, relu, emit bf16 hi/lo -----------
__global__ __launch_bounds__(256) void conv1_kernel(const float* __restrict__ img,
        const float* __restrict__ w1, const float* __restrict__ b1,
        ushort* __restrict__ c1h, ushort* __restrict__ c1l) {
    int bid = blockIdx.x;            // b*20 + oh
    int b = bid / 20, oh = bid % 20;
    __shared__ float simg[252];
    int t = threadIdx.x;
    if (t < 252) simg[t] = img[b * 784 + oh * 28 + t];
    __syncthreads();
    float acc[20];
#pragma unroll
    for (int ow = 0; ow < 20; ++ow) acc[ow] = 0.f;
    for (int kh = 0; kh < 9; ++kh) {
        float row[28];
#pragma unroll
        for (int c = 0; c < 28; ++c) row[c] = simg[kh * 28 + c];
#pragma unroll
        for (int kw = 0; kw < 9; ++kw) {
            float wv = w1[(kh * 9 + kw) * 256 + t];
#pragma unroll
            for (int ow = 0; ow < 20; ++ow) acc[ow] += row[kw + ow] * wv;
        }
    }
    float bias = b1[t];
    size_t opos = ((size_t)(b * 20 + oh) * 20) * 256 + t;
#pragma unroll
    for (int ow = 0; ow < 20; ++ow) {
        float x = fmaxf(acc[ow] + bias, 0.f);
        ushort h = bf16_rne(x);
        c1h[opos + (size_t)ow * 256] = h;
        c1l[opos + (size_t)ow * 256] = bf16_rne(x - bf16_to_f(h));
    }
}

// -------- w2 [20736][256] fp32 -> w2t hi/lo [256][20736] bf16 -------------------
__global__ __launch_bounds__(256) void prep_w2t_kernel(const float* __restrict__ w2,
        ushort* __restrict__ w2th, ushort* __restrict__ w2tl) {
    int kt = blockIdx.x, nt = blockIdx.y;   // 324 x 4
    __shared__ float tile[64][65];
    int t = threadIdx.x;
    int tn = t & 63, t4 = t >> 6;
#pragma unroll
    for (int i = 0; i < 16; ++i) {
        int k = i * 4 + t4;
        tile[k][tn] = w2[(size_t)(kt * 64 + k) * 256 + nt * 64 + tn];
    }
    __syncthreads();
    int tk = t & 63;
#pragma unroll
    for (int i = 0; i < 16; ++i) {
        int n = i * 4 + t4;
        float x = tile[tk][n];
        ushort h = bf16_rne(x);
        ushort lo = bf16_rne(x - bf16_to_f(h));
        size_t o = (size_t)(nt * 64 + n) * 20736 + kt * 64 + tk;
        w2th[o] = h; w2tl[o] = lo;
    }
}

// -------- conv2 MFMA GEMM: split bf16 (hi/lo, 3 terms), fp32 partials -----------
// BM=64, BN=128, BK=64: 48 MFMA/wave per barrier pair (2x R5). 48 KB LDS.
// Row = 64 ushorts (128 B) = 8 slots of 8; XOR swizzle slot^(row&7): conflict-free
// on both ds_write_b128 and ds_read_b128 (each 4-bank slot-group gets 8 words/bank).
// 1-D grid + XCD chunked swizzle: 72 mt-blocks of one (nt,ks) group contiguous
// per XCD chunk -> B panel L2-resident per XCD, adjacent groups share A k-slices.
#define LDS_AH 0
#define LDS_AL 4096
#define LDS_BH 8192
#define LDS_BL 16384
__global__ __launch_bounds__(256) void conv2_mfma_kernel(
        const ushort* __restrict__ c1h, const ushort* __restrict__ c1l,
        const ushort* __restrict__ w2th, const ushort* __restrict__ w2tl,
        float* __restrict__ part, int nsteps, int nwg) {
    int bid = blockIdx.x;
    int v = (bid & 7) * (nwg >> 3) + (bid >> 3);   // bijective: 8 | nwg
    int mt = v % 72, grp = v / 72;
    int nt = grp & 1, ks = grp >> 1;
    int t = threadIdx.x;
    int m0 = mt * 64, n0 = nt * 128;
    __shared__ __attribute__((aligned(16))) ushort lds[24576];   // 48 KB

    // staging: thread t -> rows (sr, sr+32 [A]; sr,+32,+64,+96 [B]), slot sc
    int sr = t >> 3, sc = t & 7;
    int mA0 = m0 + sr, mA1 = m0 + sr + 32;
    int b0_ = mA0 / 36, r0_ = mA0 % 36;
    int b1_ = mA1 / 36, r1_ = mA1 % 36;
    int pb0 = ((b0_ * 20 + (r0_ / 6) * 2) * 20 + (r0_ % 6) * 2) * 256;
    int pb1 = ((b1_ * 20 + (r1_ / 6) * 2) * 20 + (r1_ % 6) * 2) * 256;
    size_t wb = (size_t)(n0 + sr) * 20736 + sc * 8;
    int wOff = sr * 64 + ((sc ^ (sr & 7)) * 8);    // rows+32k: same xor, +2048

    int lane = t & 63, wave = t >> 6;
    int l15 = lane & 15, g = lane >> 4;
    int wrb = (wave >> 1) * 32, wcb = (wave & 1) * 64;

    floatx4 acc[2][4];
#pragma unroll
    for (int mi = 0; mi < 2; ++mi)
#pragma unroll
        for (int nj = 0; nj < 4; ++nj) acc[mi][nj] = (floatx4)0.f;

    int st0 = ks * nsteps;
    uint4 A0h, A1h, A0l, A1l, B0h, B1h, B2h, B3h, B0l, B1l, B2l, B3l;
#define LOADG64(ST) { \
        int kb = (ST) * 64; \
        int khkw = kb >> 8; int kh = khkw / 9, kw = khkw - kh * 9; \
        int ao = (kh * 20 + kw) * 256 + (kb & 255) + sc * 8; \
        A0h = *(const uint4*)(c1h + pb0 + ao); \
        A1h = *(const uint4*)(c1h + pb1 + ao); \
        A0l = *(const uint4*)(c1l + pb0 + ao); \
        A1l = *(const uint4*)(c1l + pb1 + ao); \
        size_t bo = wb + kb; \
        B0h = *(const uint4*)(w2th + bo); \
        B1h = *(const uint4*)(w2th + bo + (size_t)32 * 20736); \
        B2h = *(const uint4*)(w2th + bo + (size_t)64 * 20736); \
        B3h = *(const uint4*)(w2th + bo + (size_t)96 * 20736); \
        B0l = *(const uint4*)(w2tl + bo); \
        B1l = *(const uint4*)(w2tl + bo + (size_t)32 * 20736); \
        B2l = *(const uint4*)(w2tl + bo + (size_t)64 * 20736); \
        B3l = *(const uint4*)(w2tl + bo + (size_t)96 * 20736); }

    LOADG64(st0);
    for (int st = 0; st < nsteps; ++st) {
        __syncthreads();                 // all waves done reading LDS
        *(uint4*)&lds[LDS_AH + wOff]        = A0h;
        *(uint4*)&lds[LDS_AH + wOff + 2048] = A1h;
        *(uint4*)&lds[LDS_AL + wOff]        = A0l;
        *(uint4*)&lds[LDS_AL + wOff + 2048] = A1l;
        *(uint4*)&lds[LDS_BH + wOff]        = B0h;
        *(uint4*)&lds[LDS_BH + wOff + 2048] = B1h;
        *(uint4*)&lds[LDS_BH + wOff + 4096] = B2h;
        *(uint4*)&lds[LDS_BH + wOff + 6144] = B3h;
        *(uint4*)&lds[LDS_BL + wOff]        = B0l;
        *(uint4*)&lds[LDS_BL + wOff + 2048] = B1l;
        *(uint4*)&lds[LDS_BL + wOff + 4096] = B2l;
        *(uint4*)&lds[LDS_BL + wOff + 6144] = B3l;
        __syncthreads();
        if (st + 1 < nsteps) LOADG64(st0 + st + 1);   // prefetch during compute

#pragma unroll
        for (int kk = 0; kk < 2; ++kk) {
            int sl = kk * 4 + g;
            short8 ah[2], al[2], bh[4], bl[4];
#pragma unroll
            for (int mi = 0; mi < 2; ++mi) {
                int r = wrb + mi * 16 + l15;
                int ro = r * 64 + ((sl ^ (r & 7)) * 8);
                ah[mi] = *(const short8*)&lds[LDS_AH + ro];
                al[mi] = *(const short8*)&lds[LDS_AL + ro];
            }
#pragma unroll
            for (int nj = 0; nj < 4; ++nj) {
                int c = wcb + nj * 16 + l15;
                int co = c * 64 + ((sl ^ (c & 7)) * 8);
                bh[nj] = *(const short8*)&lds[LDS_BH + co];
                bl[nj] = *(const short8*)&lds[LDS_BL + co];
            }
#pragma unroll
            for (int mi = 0; mi < 2; ++mi)
#pragma unroll
                for (int nj = 0; nj < 4; ++nj) {
                    acc[mi][nj] = __builtin_amdgcn_mfma_f32_16x16x32_bf16(ah[mi], bh[nj], acc[mi][nj], 0, 0, 0);
                    acc[mi][nj] = __builtin_amdgcn_mfma_f32_16x16x32_bf16(ah[mi], bl[nj], acc[mi][nj], 0, 0, 0);
                    acc[mi][nj] = __builtin_amdgcn_mfma_f32_16x16x32_bf16(al[mi], bh[nj], acc[mi][nj], 0, 0, 0);
                }
        }
    }
    size_t obase = (size_t)ks * M2 * 256;
#pragma unroll
    for (int mi = 0; mi < 2; ++mi)
#pragma unroll
        for (int nj = 0; nj < 4; ++nj) {
            int col = n0 + wcb + nj * 16 + l15;
            int rowb = m0 + wrb + mi * 16 + (lane >> 4) * 4;
#pragma unroll
            for (int r = 0; r < 4; ++r)
                part[obase + (size_t)(rowb + r) * 256 + col] = acc[mi][nj][r];
        }
}

// -------- reduce k-split partials + bias + relu + squash(8) -> pc ---------------
__global__ __launch_bounds__(256) void squash_pc_kernel(const float* __restrict__ part,
        const float* __restrict__ b2, float* __restrict__ pc, int nsplit) {
    int m = blockIdx.x;
    int n = threadIdx.x;
    size_t idx = (size_t)m * 256 + n;
    const size_t stride = (size_t)M2 * 256;
    float v = 0.f;
    for (int s = 0; s < nsplit; ++s) v += part[idx + s * stride];
    v = fmaxf(v + b2[n], 0.f);
    float sq = v * v;
    sq += __shfl_xor(sq, 1, 8);
    sq += __shfl_xor(sq, 2, 8);
    sq += __shfl_xor(sq, 4, 8);
    float scale = sq / ((1.f + sq) * sqrtf(sq + EPSQ));
    pc[idx] = v * scale;
}

// -------- s1 partials: grid (144 i-chunks x 8 b-groups), W in regs --------------
__global__ __launch_bounds__(192) void s1part_kernel(const float* __restrict__ Wm,
        const float* __restrict__ pc, float* __restrict__ s1p) {
    int ic = blockIdx.x, bg = blockIdx.y;
    int i0 = ic * 8, b0 = bg * 16;
    int t = threadIdx.x;
    __shared__ float pcl[16][68];
    for (int e = t; e < 1024; e += 192) {
        int bl = e >> 6, off = e & 63;
        pcl[bl][off] = pc[(size_t)(b0 + bl) * 9216 + i0 * 8 + off];
    }
    __syncthreads();
    if (t >= 160) return;
    float4 w[8][2];
#pragma unroll
    for (int ii = 0; ii < 8; ++ii) {
        const float4* wp = (const float4*)&Wm[(size_t)(i0 + ii) * 1280 + t * 8];
        w[ii][0] = wp[0]; w[ii][1] = wp[1];
    }
    for (int bl = 0; bl < 16; ++bl) {
        float s = 0.f;
#pragma unroll
        for (int ii = 0; ii < 8; ++ii) {
            const float* p = &pcl[bl][ii * 8];
            s += DOT8(w[ii][0], w[ii][1], p);
        }
        s1p[(size_t)ic * 20480 + (b0 + bl) * 160 + t] = s;
    }
}

// -------- v1 = squash_d(0.1 * sum of 144 partials), grid (b*10+j) ---------------
__global__ __launch_bounds__(64) void v1red_kernel(const float* __restrict__ s1p,
        float* __restrict__ v1) {
    int bj = blockIdx.x;
    int b = bj / 10, j = bj % 10;
    int t = threadIdx.x;
    int d = t & 15, kq = t >> 4;
    size_t base = (size_t)b * 160 + j * 16 + d;
    float s = 0.f;
    for (int kc = kq; kc < 144; kc += 4) s += s1p[(size_t)kc * 20480 + base];
    s += __shfl_xor(s, 16, 64);
    s += __shfl_xor(s, 32, 64);
    s *= 0.1f;
    float sq = s * s;
    sq += __shfl_xor(sq, 1, 16);
    sq += __shfl_xor(sq, 2, 16);
    sq += __shfl_xor(sq, 4, 16);
    sq += __shfl_xor(sq, 8, 16);
    float v = s * sq / ((1.f + sq) * sqrtf(sq + EPSQ));
    if (t < 16) v1[b * 160 + j * 16 + d] = v;
}

// -------- c2 (agreement+softmax) + s2 partials, u recomputed; grid (144 x 8) ----
__global__ __launch_bounds__(192) void c2s2_kernel(const float* __restrict__ Wm,
        const float* __restrict__ pc, const float* __restrict__ v1,
        float* __restrict__ s2p) {
    int ic = blockIdx.x, bg = blockIdx.y;
    int i0 = ic * 8, b0 = bg * 16;
    int t = threadIdx.x;
    __shared__ float pcl[16][68];
    __shared__ float uvl[8][16][10];
    for (int e = t; e < 1024; e += 192) {
        int bl = e >> 6, off = e & 63;
        pcl[bl][off] = pc[(size_t)(b0 + bl) * 9216 + i0 * 8 + off];
    }
    __syncthreads();
    int j = t >> 4;
    float4 w[8][2];
    if (t < 160) {
#pragma unroll
        for (int ii = 0; ii < 8; ++ii) {
            const float4* wp = (const float4*)&Wm[(size_t)(i0 + ii) * 1280 + t * 8];
            w[ii][0] = wp[0]; w[ii][1] = wp[1];
        }
        for (int bl = 0; bl < 16; ++bl) {
            float vv = v1[(b0 + bl) * 160 + t];
#pragma unroll
            for (int ii = 0; ii < 8; ++ii) {
                const float* p = &pcl[bl][ii * 8];
                float u = DOT8(w[ii][0], w[ii][1], p);
                float pr = u * vv;
                pr += __shfl_xor(pr, 1, 16);
                pr += __shfl_xor(pr, 2, 16);
                pr += __shfl_xor(pr, 4, 16);
                pr += __shfl_xor(pr, 8, 16);
                if ((t & 15) == 0) uvl[ii][bl][j] = pr;
            }
        }
    }
    __syncthreads();
    if (t < 128) {
        int ii = t >> 4, bl = t & 15;
        float* uv = uvl[ii][bl];
        float mx = uv[0];
#pragma unroll
        for (int jj = 1; jj < 10; ++jj) mx = fmaxf(mx, uv[jj]);
        float sum = 0.f;
        float ex[10];
#pragma unroll
        for (int jj = 0; jj < 10; ++jj) { ex[jj] = expf(uv[jj] - mx); sum += ex[jj]; }
        float inv = 1.f / sum;
#pragma unroll
        for (int jj = 0; jj < 10; ++jj) uv[jj] = ex[jj] * inv;
    }
    __syncthreads();
    if (t >= 160) return;
    for (int bl = 0; bl < 16; ++bl) {
        float acc = 0.f;
#pragma unroll
        for (int ii = 0; ii < 8; ++ii) {
            const float* p = &pcl[bl][ii * 8];
            float u = DOT8(w[ii][0], w[ii][1], p);
            acc += uvl[ii][bl][j] * u;
        }
        s2p[(size_t)ic * 20480 + (b0 + bl) * 160 + t] = acc;
    }
}

// -------- v2 = squash_d(sum partials), norms -> out, grid (b*10+j) --------------
__global__ __launch_bounds__(64) void v2red_kernel(const float* __restrict__ s2p,
        float* __restrict__ v2, float* __restrict__ nrm, float* __restrict__ out) {
    int bj = blockIdx.x;
    int b = bj / 10, j = bj % 10;
    int t = threadIdx.x;
    int d = t & 15, kq = t >> 4;
    size_t base = (size_t)b * 160 + j * 16 + d;
    float s = 0.f;
    for (int kc = kq; kc < 144; kc += 4) s += s2p[(size_t)kc * 20480 + base];
    s += __shfl_xor(s, 16, 64);
    s += __shfl_xor(s, 32, 64);
    float sq = s * s;
    sq += __shfl_xor(sq, 1, 16);
    sq += __shfl_xor(sq, 2, 16);
    sq += __shfl_xor(sq, 4, 16);
    sq += __shfl_xor(sq, 8, 16);
    float v = s * sq / ((1.f + sq) * sqrtf(sq + EPSQ));
    float vsq = v * v;
    vsq += __shfl_xor(vsq, 1, 16);
    vsq += __shfl_xor(vsq, 2, 16);
    vsq += __shfl_xor(vsq, 4, 16);
    vsq += __shfl_xor(vsq, 8, 16);
    float norm = sqrtf(vsq + EPSQ);
    if (t < 16) v2[b * 160 + j * 16 + d] = v;
    if (t == 0) { nrm[b * 10 + j] = norm; out[b * 10 + j] = norm; }
}

// -------- fc1 with fused argmax (y_pred) + target mask --------------------------
__global__ __launch_bounds__(256) void fc1_kernel(const float* __restrict__ v2,
        const float* __restrict__ nrm, const int* __restrict__ target,
        const float* __restrict__ w, const float* __restrict__ bias,
        float* __restrict__ ypred, float* __restrict__ h1) {
    int nc = blockIdx.x, b = blockIdx.y;
    int t = threadIdx.x;
    __shared__ float sk[160];
    __shared__ float nl[10];
    if (t < 160) {
        float v = v2[b * 160 + t];
        sk[t] = ((t >> 4) == target[b]) ? v : 0.f;
    }
    if (t < 10) nl[t] = nrm[b * 10 + t];
    __syncthreads();
    if (nc == 0 && t == 0) {
        float best = nl[0]; int am = 0;
#pragma unroll
        for (int jj = 1; jj < 10; ++jj) if (nl[jj] > best) { best = nl[jj]; am = jj; }
        ypred[b] = (float)am;
    }
    int n = nc * 256 + t;
    float acc = bias[n];
    for (int k = 0; k < 160; ++k) acc += sk[k] * w[k * 512 + n];
    h1[(size_t)b * 512 + n] = fmaxf(acc, 0.f);
}

// -------- dense layers: relu (ACT=0) or sigmoid (ACT=1) -------------------------
template <int KDIM, int ACT>
__global__ __launch_bounds__(256) void fc_kernel(const float* __restrict__ in,
        const float* __restrict__ w, const float* __restrict__ bias,
        float* __restrict__ out, int N) {
    int b = blockIdx.y;
    int n = blockIdx.x * 256 + threadIdx.x;
    __shared__ float sk[KDIM];
    for (int r = threadIdx.x; r < KDIM; r += 256) sk[r] = in[(size_t)b * KDIM + r];
    __syncthreads();
    if (n >= N) return;
    float acc = bias[n];
    for (int k = 0; k < KDIM; ++k) acc += sk[k] * w[(size_t)k * N + n];
    if (ACT == 0) acc = fmaxf(acc, 0.f);
    else acc = 1.f / (1.f + expf(-acc));
    out[(size_t)b * N + n] = acc;
}

extern "C" void kernel_launch(void* const* d_in, const int* in_sizes, int n_in,
                              void* d_out, int out_size, void* d_ws, size_t ws_size,
                              hipStream_t stream) {
    const float* image = (const float*)d_in[0];
    const int*   target = (const int*)d_in[1];
    const float* w1  = (const float*)d_in[2];
    const float* b1  = (const float*)d_in[3];
    const float* w2  = (const float*)d_in[4];
    const float* b2  = (const float*)d_in[5];
    const float* Wm  = (const float*)d_in[6];
    const float* d1w = (const float*)d_in[7];
    const float* d1b = (const float*)d_in[8];
    const float* d2w = (const float*)d_in[9];
    const float* d2b = (const float*)d_in[10];
    const float* dow = (const float*)d_in[11];
    const float* dob = (const float*)d_in[12];
    float* out = (float*)d_out;
    float* ws  = (float*)d_ws;

    ushort* c1h  = (ushort*)(ws + WS_C1H);
    ushort* c1l  = (ushort*)(ws + WS_C1L);
    ushort* w2th = (ushort*)(ws + WS_W2TH);
    ushort* w2tl = (ushort*)(ws + WS_W2TL);

    // adaptive k-split (must give even 32-step count for BK=64 pairing):
    // need (18,415,616 + k*1,179,648)*4 bytes of ws
    int ksplit = 4;
    if (ws_size >= (size_t)(18415616 + 18 * 1179648) * 4) ksplit = 18;
    else if (ws_size >= (size_t)(18415616 + 12 * 1179648) * 4) ksplit = 12;
    else if (ws_size >= (size_t)(18415616 + 6 * 1179648) * 4) ksplit = 6;
    int nsteps = KSTEPS / ksplit / 2;     // 64-wide K-steps per split
    int nwg = 144 * ksplit;               // always divisible by 8

    conv1_kernel<<<2560, 256, 0, stream>>>(image, w1, b1, c1h, c1l);
    prep_w2t_kernel<<<dim3(324, 4), 256, 0, stream>>>(w2, w2th, w2tl);
    conv2_mfma_kernel<<<nwg, 256, 0, stream>>>(c1h, c1l, w2th, w2tl,
                                               ws + WS_CPART, nsteps, nwg);
    squash_pc_kernel<<<4608, 256, 0, stream>>>(ws + WS_CPART, b2, ws + WS_PC, ksplit);
    s1part_kernel<<<dim3(144, 8), 192, 0, stream>>>(Wm, ws + WS_PC, ws + WS_S1P);
    v1red_kernel<<<1280, 64, 0, stream>>>(ws + WS_S1P, ws + WS_V1);
    c2s2_kernel<<<dim3(144, 8), 192, 0, stream>>>(Wm, ws + WS_PC, ws + WS_V1, ws + WS_S2P);
    v2red_kernel<<<1280, 64, 0, stream>>>(ws + WS_S2P, ws + WS_V2, ws + WS_NRM, out);
    fc1_kernel<<<dim3(2, 128), 256, 0, stream>>>(ws + WS_V2, ws + WS_NRM, target,
                                                 d1w, d1b, out + 1280, ws + WS_H1);
    fc_kernel<512, 0><<<dim3(4, 128), 256, 0, stream>>>(ws + WS_H1, d2w, d2b, ws + WS_H2, 1024);
    fc_kernel<1024, 1><<<dim3(4, 128), 256, 0, stream>>>(ws + WS_H2, dow, dob, out + 1408, 784);
}